// Round 3
// baseline (82.817 us; speedup 1.0000x reference)
//
#include <hip/hip_runtime.h>
#include <math.h>

// EntropyPatcher: B=256 rows, L=8192 tokens in [0,5), E=64.
// out = concat(blt_features[B,E], entropy[B,L]) as float32.
// Identity: blt = (sum_patches relu(mean*w1+b1) / P) @ w2^T + b2.
//
// One block of 1024 threads (16 waves) per row, 256 blocks = 1/CU.
// Entropy: 4-bit-packed sliding window counts; per position just
//   ent = trip4096[s & 0xFFF] + pair256[(s>>12) & 0xFF]   (2 LDS reads).
// Edges (8 pos/row) use denominator-specific 16-entry tables (no logs).
// Patch walk: per-chunk exit tables in VGPR masks, composed via a
// packed-nibble function-composition shuffle scan; chunk walk batches
// 4 boundary loads per waitcnt.

constexpr int B_ = 256;
constexpr int L_ = 8192;
constexpr int E_ = 64;
constexpr int T_ = 1024;     // threads/block (16 waves)
constexpr int PT = 8;        // positions per thread
constexpr int CHUNK = 128;
constexpr int NCH = L_ / CHUNK;  // 64
constexpr int MAXPC = 44;        // ceil(128/3)=43 max patches/chunk (+1 pad)

__global__ __launch_bounds__(1024)
void entropy_patcher_kernel(const int* __restrict__ x,
                            const float* __restrict__ w1,
                            const float* __restrict__ b1,
                            const float* __restrict__ w2,
                            const float* __restrict__ b2,
                            float* __restrict__ dout) {
  __shared__ __align__(16) unsigned char tok8p[8 + L_ + 8];  // sentinel pads
  __shared__ __align__(16) float csBuf[L_ + 4];              // cs[0..L]
  __shared__ __align__(16) float trip[4096];                 // f(a)+f(b)+f(c), idx a|b<<4|c<<8
  __shared__ __align__(16) float pair256[256];               // f(d)+f(e), idx d|e<<4
  __shared__ __align__(16) float fTab[16];                   // f(k) = -(k/9)log2(k/9+eps)
  __shared__ __align__(16) float edgeF[64];                  // [d-5][k], d=5..8
  __shared__ __align__(16) float meanbuf[NCH][MAXPC];
  __shared__ __align__(16) unsigned char maskBytes[T_];      // bit p: ent[p] > 1.5
  __shared__ unsigned char exitT[NCH][12];
  __shared__ float rcpTab[13];
  __shared__ int cntC[NCH];
  __shared__ int waveTot[16];
  __shared__ float Sred[16][E_];
  __shared__ float partG[16][E_];
  __shared__ float avgv[E_];
  __shared__ int PcountS;

  const int tid  = threadIdx.x;
  const int lane = tid & 63;
  const int wv   = tid >> 6;
  const int b    = blockIdx.x;

  const int* xr = x + b * L_;
  float* entOut = dout + (size_t)B_ * E_ + (size_t)b * L_;

  // ---------- Phase A: issue global loads; build base tables while in flight ----------
  const int4 v0 = ((const int4*)xr)[2 * tid];
  const int4 v1 = ((const int4*)xr)[2 * tid + 1];

  if (tid < 16) {                        // fTab (denominator 9)
    float pk = (float)tid / 9.0f;
    fTab[tid] = (tid <= 9) ? -(pk * log2f(pk + 1e-12f)) : 0.0f;
  } else if (tid < 80) {                 // edgeF: d = 5..8
    int j = (tid - 16) >> 4, k = (tid - 16) & 15;
    int d = j + 5;
    float pk = (float)k / (float)d;
    edgeF[tid - 16] = (k <= d) ? -(pk * log2f(pk + 1e-12f)) : 0.0f;
  } else if (tid >= 96 && tid < 109) {
    int n = tid - 96;
    rcpTab[n] = 1.0f / (float)(n == 0 ? 1 : n);
  }
  __syncthreads();                       // fTab/edgeF visible

  // derived tables (conflict-free by lane structure: low nibble == lane&15)
  #pragma unroll
  for (int i = 0; i < 4; ++i) {
    int t = tid + 1024 * i;
    trip[t] = fTab[t & 15] + fTab[(t >> 4) & 15] + fTab[(t >> 8) & 15];
  }
  if (tid < 256) pair256[tid] = fTab[tid & 15] + fTab[tid >> 4];

  // tokens -> LDS bytes (+0xFF sentinels)
  unsigned pw0 = (unsigned)v0.x | ((unsigned)v0.y << 8) |
                 ((unsigned)v0.z << 16) | ((unsigned)v0.w << 24);
  unsigned pw1 = (unsigned)v1.x | ((unsigned)v1.y << 8) |
                 ((unsigned)v1.z << 16) | ((unsigned)v1.w << 24);
  *(uint2*)(tok8p + 8 + 8 * tid) = make_uint2(pw0, pw1);
  if (tid == 0) *(uint2*)(tok8p) = make_uint2(~0u, ~0u);
  if (tid == 1) *(uint2*)(tok8p + 8 + L_) = make_uint2(~0u, ~0u);
  __syncthreads();                       // tok8p + trip/pair256 visible

  // ---------- Phase B: sliding-window entropy via 4-bit packed counts ----------
  unsigned long long tw0 = *(const unsigned long long*)(tok8p + 8 * tid);
  unsigned long long tw1 = *(const unsigned long long*)(tok8p + 8 * tid + 8);
  unsigned long long tw2 = *(const unsigned long long*)(tok8p + 8 * tid + 16);
  unsigned code[20];                     // local l = g - (8t-8); use 4..19
  #pragma unroll
  for (int l = 4; l < 20; ++l) {
    unsigned byte = (l < 8)  ? (unsigned)((tw0 >> (8 * l)) & 0xff)
                  : (l < 16) ? (unsigned)((tw1 >> (8 * (l - 8))) & 0xff)
                             : (unsigned)((tw2 >> (8 * (l - 16))) & 0xff);
    if (byte > 5u) byte = 5u;            // sentinel -> bit 20 (outside fields)
    code[l] = 1u << (4 * byte);          // counts in 4-bit fields (max 9 < 16)
  }
  unsigned s = 0;
  #pragma unroll
  for (int l = 4; l <= 12; ++l) s += code[l];   // window of p = 8t
  float entv[PT];
  entv[0] = trip[s & 4095u] + pair256[(s >> 12) & 255u];
  #pragma unroll
  for (int q = 1; q < PT; ++q) {
    s += code[q + 12] - code[q + 3];
    entv[q] = trip[s & 4095u] + pair256[(s >> 12) & 255u];
  }
  if (tid == 0 || tid == T_ - 1) {       // 8 clipped-window positions, table-driven
    #pragma unroll
    for (int q = 0; q < PT; ++q) {
      int p = 8 * tid + q;
      if (p < 4 || p >= L_ - 4) {
        unsigned ss = 0;
        for (int l = q + 4; l <= q + 12; ++l) ss += code[l];
        int d = (p < 4) ? (p + 5) : (L_ + 4 - p);     // window size 5..8
        const float* fd = &edgeF[(d - 5) * 16];
        entv[q] = fd[ss & 15u] + fd[(ss >> 4) & 15u] + fd[(ss >> 8) & 15u]
                + fd[(ss >> 12) & 15u] + fd[(ss >> 16) & 15u];
      }
    }
  }
  ((float4*)entOut)[2 * tid]     = make_float4(entv[0], entv[1], entv[2], entv[3]);
  ((float4*)entOut)[2 * tid + 1] = make_float4(entv[4], entv[5], entv[6], entv[7]);
  unsigned mbyte = 0;
  #pragma unroll
  for (int q = 0; q < PT; ++q) mbyte |= (entv[q] > 1.5f ? 1u : 0u) << q;
  maskBytes[tid] = (unsigned char)mbyte;

  // ---------- Phase C: exclusive token prefix sums (exact ints in fp32) ----------
  int tk[8];
  #pragma unroll
  for (int j = 0; j < 4; ++j) {
    tk[j]     = (int)((pw0 >> (8 * j)) & 0xffu);
    tk[4 + j] = (int)((pw1 >> (8 * j)) & 0xffu);
  }
  int ls = tk[0] + tk[1] + tk[2] + tk[3] + tk[4] + tk[5] + tk[6] + tk[7];
  int incl = ls;
  #pragma unroll
  for (int d = 1; d < 64; d <<= 1) {
    int up = __shfl_up(incl, d, 64);
    if (lane >= d) incl += up;
  }
  if (lane == 63) waveTot[wv] = incl;
  __syncthreads();                       // publishes waveTot + maskBytes
  int base = 0;
  #pragma unroll
  for (int q = 0; q < 16; ++q) base += (q < wv) ? waveTot[q] : 0;
  float acc = (float)(base + incl - ls);
  {
    float4 c0, c1;
    c0.x = acc; acc += (float)tk[0]; c0.y = acc; acc += (float)tk[1];
    c0.z = acc; acc += (float)tk[2]; c0.w = acc; acc += (float)tk[3];
    c1.x = acc; acc += (float)tk[4]; c1.y = acc; acc += (float)tk[5];
    c1.z = acc; acc += (float)tk[6]; c1.w = acc; acc += (float)tk[7];
    ((float4*)csBuf)[2 * tid] = c0; ((float4*)csBuf)[2 * tid + 1] = c1;
    if (tid == T_ - 1) csBuf[L_] = acc;
  }

  // ---------- Phase D: per-(chunk, entry 0..11) exit walk, masks in VGPRs ----------
  unsigned long long m0 = 0, m1 = 0;
  if (tid < 768) {
    int c = tid & 63, o = tid >> 6;
    m0 = *(const unsigned long long*)(maskBytes + 16 * c);
    m1 = *(const unsigned long long*)(maskBytes + 16 * c + 8);
    int p = o;
    while (p < CHUNK) {
      unsigned long long mm = (p & 64) ? m1 : m0;
      p += ((mm >> (p & 63)) & 1ULL) ? 3 : 12;
    }
    exitT[c][o] = (unsigned char)(p - CHUNK);
  }
  __syncthreads();                       // exitT + csBuf ready

  // ---------- Compose exit maps (wave 0): packed 12x4-bit shuffle scan ----------
  if (tid < 64) {
    const unsigned* ep = (const unsigned*)&exitT[tid][0];  // stride 12, 4-aligned
    unsigned u0 = ep[0], u1 = ep[1], u2 = ep[2];
    auto nib = [](unsigned w) {
      return (w & 0xFu) | ((w >> 4) & 0xF0u) | ((w >> 8) & 0xF00u) | ((w >> 12) & 0xF000u);
    };
    unsigned long long tab = (unsigned long long)nib(u0)
                           | ((unsigned long long)nib(u1) << 16)
                           | ((unsigned long long)nib(u2) << 32);
    #pragma unroll
    for (int d = 1; d < 64; d <<= 1) {
      unsigned long long other =
          (unsigned long long)__shfl_up((long long)tab, d, 64);
      if (lane >= d) {
        unsigned long long nt = 0;
        #pragma unroll
        for (int e = 0; e < 12; ++e) {
          unsigned oe  = (unsigned)((other >> (4 * e)) & 15ULL);
          unsigned val = (unsigned)((tab >> (4 * oe)) & 15ULL);
          nt |= (unsigned long long)val << (4 * e);
        }
        tab = nt;
      }
    }
    unsigned long long prev = (unsigned long long)__shfl_up((long long)tab, 1, 64);
    int myOff = (lane == 0) ? 0 : (int)(prev & 15ULL);

    // ---------- Phase E: walk own chunk; batch 4 boundary loads per wait ----------
    const int c = tid;
    const int end = CHUNK * c + CHUNK;
    int p = CHUNK * c + myOff;
    int pb = p;
    int n = 0;
    float csp = csBuf[p];
    while (p < end) {
      int j0, j1, j2, j3;                // plan 4 boundaries, VALU only
      {
        int pp = p;
        int lp = pp & 127;
        unsigned long long mm = (lp & 64) ? m1 : m0;
        int ps = ((mm >> (lp & 63)) & 1ULL) ? 3 : 12;
        int j = pp + ps; if (j > L_) j = L_;
        j0 = j; pp = j;
        bool a1 = pp < end;
        lp = pp & 127; mm = (lp & 64) ? m1 : m0;
        ps = ((mm >> (lp & 63)) & 1ULL) ? 3 : 12;
        j = pp + ps; if (j > L_) j = L_;
        j1 = a1 ? j : -1; if (a1) pp = j;
        bool a2 = pp < end && a1;
        lp = pp & 127; mm = (lp & 64) ? m1 : m0;
        ps = ((mm >> (lp & 63)) & 1ULL) ? 3 : 12;
        j = pp + ps; if (j > L_) j = L_;
        j2 = a2 ? j : -1; if (a2) pp = j;
        bool a3 = pp < end && a2;
        lp = pp & 127; mm = (lp & 64) ? m1 : m0;
        ps = ((mm >> (lp & 63)) & 1ULL) ? 3 : 12;
        j = pp + ps; if (j > L_) j = L_;
        j3 = a3 ? j : -1; if (a3) pp = j;
        p = pp;
      }
      float f0 = csBuf[j0];
      float f1 = csBuf[j1 < 0 ? 0 : j1];
      float f2 = csBuf[j2 < 0 ? 0 : j2];
      float f3 = csBuf[j3 < 0 ? 0 : j3];   // 4 reads -> one waitcnt
      meanbuf[c][n++] = (f0 - csp) * rcpTab[j0 - pb]; csp = f0; pb = j0;
      if (j1 >= 0) { meanbuf[c][n++] = (f1 - csp) * rcpTab[j1 - pb]; csp = f1; pb = j1; }
      if (j2 >= 0) { meanbuf[c][n++] = (f2 - csp) * rcpTab[j2 - pb]; csp = f2; pb = j2; }
      if (j3 >= 0) { meanbuf[c][n++] = (f3 - csp) * rcpTab[j3 - pb]; csp = f3; pb = j3; }
    }
    cntC[c] = n;
    int tot = n;
    #pragma unroll
    for (int d2 = 32; d2; d2 >>= 1) tot += __shfl_xor(tot, d2, 64);
    if (lane == 0) PcountS = tot;
  }
  __syncthreads();

  // ---------- Phase F: S[e] = sum relu(mean*w1[e]+b1[e]) over patches ----------
  {
    const float w1v = w1[lane];
    const float b1v = b1[lane];
    float S = 0.0f;
    for (int c = wv; c < NCH; c += 16) {
      int n = cntC[c];
      const float* mb = &meanbuf[c][0];
      int j = 0;
      for (; j + 4 <= n; j += 4) {
        float4 m4 = *((const float4*)(mb + j));   // broadcast b128 read
        S += fmaxf(fmaf(m4.x, w1v, b1v), 0.0f);
        S += fmaxf(fmaf(m4.y, w1v, b1v), 0.0f);
        S += fmaxf(fmaf(m4.z, w1v, b1v), 0.0f);
        S += fmaxf(fmaf(m4.w, w1v, b1v), 0.0f);
      }
      for (; j < n; ++j) S += fmaxf(fmaf(mb[j], w1v, b1v), 0.0f);
    }
    Sred[wv][lane] = S;
  }
  __syncthreads();
  if (tid < 64) {
    float sm = 0.f;
    #pragma unroll
    for (int q = 0; q < 16; ++q) sm += Sred[q][tid];
    avgv[tid] = sm / (float)PcountS;
  }
  __syncthreads();

  // ---------- Phase G: tiny matvec out = avg @ w2^T + b2 ----------
  {
    float4 wvv = *((const float4*)(w2 + lane * 64 + 4 * wv));  // one b128/thread
    float acc2 = avgv[4 * wv + 0] * wvv.x;
    acc2 = fmaf(avgv[4 * wv + 1], wvv.y, acc2);
    acc2 = fmaf(avgv[4 * wv + 2], wvv.z, acc2);
    acc2 = fmaf(avgv[4 * wv + 3], wvv.w, acc2);
    partG[wv][lane] = acc2;
  }
  __syncthreads();
  if (tid < 64) {
    float r = b2[tid];
    #pragma unroll
    for (int q = 0; q < 16; ++q) r += partG[q][tid];
    dout[(size_t)b * E_ + tid] = r;
  }
}

extern "C" void kernel_launch(void* const* d_in, const int* in_sizes, int n_in,
                              void* d_out, int out_size, void* d_ws, size_t ws_size,
                              hipStream_t stream) {
  const int*   x  = (const int*)d_in[0];
  const float* w1 = (const float*)d_in[1];
  const float* b1 = (const float*)d_in[2];
  const float* w2 = (const float*)d_in[3];
  const float* b2 = (const float*)d_in[4];
  float* out = (float*)d_out;
  entropy_patcher_kernel<<<B_, T_, 0, stream>>>(x, w1, b1, w2, b2, out);
}